// Round 12
// baseline (12.782 us; speedup 1.0000x reference)
//
#include <hip/hip_runtime.h>

// P=40000, DEG=16, CI=CO=16.
// Block = 256 threads = 4 waves = 64 points (grid = P/64 = 625, exact).
// Per wave: 16 points, R11 structure:
//   Phase A (VALU): lane l = (pt = l&15, iq = (l>>4)&3) computes
//       h[d][i=4*iq+j] = sum_n r[pt][n][d] * feat[nbr[pt][n]][4*iq+j]
//     (one dwordx4 feat load per neighbor covers 16 points).
//   Phase B (MFMA): D[16pt][16o] = sum_d H_d @ W_d^T = 3x v_mfma_f32_16x16x16f16.
//     Phase-A layout IS the A-fragment; W forms the B-fragment; C/D per m89
//     (col=lane&15, row=4*(lane>>4)+reg). No h transpose, no second barrier.
// Staging is block-wide coalesced: 768 float4 of radii + 1024 ints of bs
// across 256 lanes. LDS rows padded (52 floats / 20 ints): 16B-aligned,
// row-offsets mod 128B cover all banks 2-way -> conflict-free (2-way is free).

typedef _Float16 half4v  __attribute__((ext_vector_type(4)));
typedef float    floatx4 __attribute__((ext_vector_type(4)));

__global__ __launch_bounds__(256) void k_conv(const float* __restrict__ feat,
                                              const float* __restrict__ radii,
                                              const float* __restrict__ W,
                                              const int* __restrict__ bs,
                                              float* __restrict__ out,
                                              int P) {
    __shared__ __align__(16) float s_r[64][52];   // [local pt][n*3+d], pad 48->52
    __shared__ __align__(16) int   s_nb[64][20];  // [local pt][n],     pad 16->20

    const int tid = threadIdx.x;      // 0..255
    const int pbase = blockIdx.x * 64;

    // ---- stage radii: 64 pts x 48 floats = 768 float4, block-wide coalesced ----
    {
        const size_t lim4 = (size_t)P * 12;
#pragma unroll
        for (int c = 0; c < 3; ++c) {
            const int f4i = c * 256 + tid;                // 0..767
            const size_t gidx = (size_t)pbase * 12 + f4i;
            float4 v = make_float4(0.f, 0.f, 0.f, 0.f);
            if (gidx < lim4) v = reinterpret_cast<const float4*>(radii)[gidx];
            const int row  = f4i / 12;
            const int col4 = f4i - row * 12;
            *reinterpret_cast<float4*>(&s_r[row][col4 * 4]) = v;
        }
    }
    // ---- stage bs: 64 rows x 16 nbr ints; thread t -> row t>>2, cols (t&3)*4.. ----
    {
        const int row = tid >> 2;
        const int c0  = (tid & 3) * 4;
        const int p   = pbase + row;
        int4 v = make_int4(0, 0, 0, 0);
        if (p < P) {
            const int* bp = bs + (size_t)p * 17 + 1 + c0;   // rows are 17 ints: scalar loads
            v.x = bp[0]; v.y = bp[1]; v.z = bp[2]; v.w = bp[3];
        }
        *reinterpret_cast<int4*>(&s_nb[row][c0]) = v;
    }
    __syncthreads();

    const int l   = tid & 63;                 // lane
    const int w   = tid >> 6;                 // wave -> 16-point tile
    const int pt  = l & 15;                   // phase-A point row / phase-B o column
    const int iq  = l >> 4;                   // k-quad
    const int ptl = w * 16 + pt;              // local point index for LDS

    // ---- B-fragments from W (global, L1-hot): lane holds W[d][o=pt][4*iq..+3] ----
    half4v bw0, bw1, bw2;
    {
        const float4* Wv = reinterpret_cast<const float4*>(W);
        const float4 w0 = Wv[  0 + pt * 4 + iq];
        const float4 w1 = Wv[ 64 + pt * 4 + iq];
        const float4 w2 = Wv[128 + pt * 4 + iq];
        bw0[0]=(_Float16)w0.x; bw0[1]=(_Float16)w0.y; bw0[2]=(_Float16)w0.z; bw0[3]=(_Float16)w0.w;
        bw1[0]=(_Float16)w1.x; bw1[1]=(_Float16)w1.y; bw1[2]=(_Float16)w1.z; bw1[3]=(_Float16)w1.w;
        bw2[0]=(_Float16)w2.x; bw2[1]=(_Float16)w2.y; bw2[2]=(_Float16)w2.z; bw2[3]=(_Float16)w2.w;
    }

    // ---- neighbor row for this point: 4x b128 (4-lane broadcast, 2-way banks) ----
    int nb[16];
    {
        const int4* nb4 = reinterpret_cast<const int4*>(&s_nb[ptl][0]);
#pragma unroll
        for (int c = 0; c < 4; ++c) {
            const int4 v = nb4[c];
            nb[c*4+0] = v.x; nb[c*4+1] = v.y; nb[c*4+2] = v.z; nb[c*4+3] = v.w;
        }
    }

    // ---- Phase A: h[d][j] for i = 4*iq+j ----
    float a00=0.f,a01=0.f,a02=0.f,a03=0.f;   // d=0
    float a10=0.f,a11=0.f,a12=0.f,a13=0.f;   // d=1
    float a20=0.f,a21=0.f,a22=0.f,a23=0.f;   // d=2
    const float4* feat4 = reinterpret_cast<const float4*>(feat);
    const float4* rrow  = reinterpret_cast<const float4*>(&s_r[ptl][0]);
#pragma unroll
    for (int c = 0; c < 4; ++c) {
        const float4 r0 = rrow[c*3+0];   // {n0.d0, n0.d1, n0.d2, n1.d0}
        const float4 r1 = rrow[c*3+1];   // {n1.d1, n1.d2, n2.d0, n2.d1}
        const float4 r2 = rrow[c*3+2];   // {n2.d2, n3.d0, n3.d1, n3.d2}
        float4 f;
        f = feat4[(size_t)nb[c*4+0] * 4 + iq];
        a00+=r0.x*f.x; a01+=r0.x*f.y; a02+=r0.x*f.z; a03+=r0.x*f.w;
        a10+=r0.y*f.x; a11+=r0.y*f.y; a12+=r0.y*f.z; a13+=r0.y*f.w;
        a20+=r0.z*f.x; a21+=r0.z*f.y; a22+=r0.z*f.z; a23+=r0.z*f.w;
        f = feat4[(size_t)nb[c*4+1] * 4 + iq];
        a00+=r0.w*f.x; a01+=r0.w*f.y; a02+=r0.w*f.z; a03+=r0.w*f.w;
        a10+=r1.x*f.x; a11+=r1.x*f.y; a12+=r1.x*f.z; a13+=r1.x*f.w;
        a20+=r1.y*f.x; a21+=r1.y*f.y; a22+=r1.y*f.z; a23+=r1.y*f.w;
        f = feat4[(size_t)nb[c*4+2] * 4 + iq];
        a00+=r1.z*f.x; a01+=r1.z*f.y; a02+=r1.z*f.z; a03+=r1.z*f.w;
        a10+=r1.w*f.x; a11+=r1.w*f.y; a12+=r1.w*f.z; a13+=r1.w*f.w;
        a20+=r2.x*f.x; a21+=r2.x*f.y; a22+=r2.x*f.z; a23+=r2.x*f.w;
        f = feat4[(size_t)nb[c*4+3] * 4 + iq];
        a00+=r2.y*f.x; a01+=r2.y*f.y; a02+=r2.y*f.z; a03+=r2.y*f.w;
        a10+=r2.z*f.x; a11+=r2.z*f.y; a12+=r2.z*f.z; a13+=r2.z*f.w;
        a20+=r2.w*f.x; a21+=r2.w*f.y; a22+=r2.w*f.z; a23+=r2.w*f.w;
    }

    // ---- A-fragments (f16) ----
    half4v ah0, ah1, ah2;
    ah0[0]=(_Float16)a00; ah0[1]=(_Float16)a01; ah0[2]=(_Float16)a02; ah0[3]=(_Float16)a03;
    ah1[0]=(_Float16)a10; ah1[1]=(_Float16)a11; ah1[2]=(_Float16)a12; ah1[3]=(_Float16)a13;
    ah2[0]=(_Float16)a20; ah2[1]=(_Float16)a21; ah2[2]=(_Float16)a22; ah2[3]=(_Float16)a23;

    // ---- Phase B: 3 chained MFMAs ----
    floatx4 acc = {0.f, 0.f, 0.f, 0.f};
    acc = __builtin_amdgcn_mfma_f32_16x16x16f16(ah0, bw0, acc, 0, 0, 0);
    acc = __builtin_amdgcn_mfma_f32_16x16x16f16(ah1, bw1, acc, 0, 0, 0);
    acc = __builtin_amdgcn_mfma_f32_16x16x16f16(ah2, bw2, acc, 0, 0, 0);

    // ---- store: D col = pt (=o), row = 4*iq+j (= point within wave tile) ----
    const int prow_base = pbase + w * 16 + 4 * iq;
#pragma unroll
    for (int j = 0; j < 4; ++j) {
        const int prow = prow_base + j;
        if (prow < P) out[(size_t)prow * 16 + pt] = acc[j];
    }
}

extern "C" void kernel_launch(void* const* d_in, const int* in_sizes, int n_in,
                              void* d_out, int out_size, void* d_ws, size_t ws_size,
                              hipStream_t stream) {
    const float* feat  = (const float*)d_in[0];   // [P,16] f32
    const float* radii = (const float*)d_in[1];   // [E,3]  f32
    const float* W     = (const float*)d_in[2];   // [3,16,16] f32
    const int*   bs    = (const int*)d_in[3];     // [P,17] i32
    float* out = (float*)d_out;                   // [P,16] f32

    const int P = in_sizes[0] / 16;
    const int grid = (P + 63) / 64;
    k_conv<<<grid, 256, 0, stream>>>(feat, radii, W, bs, out, P);
}

// Round 13
// 12.008 us; speedup vs baseline: 1.0644x; 1.0644x over previous
//
#include <hip/hip_runtime.h>

// P=40000, DEG=16, CI=CO=16.  [FINAL: best-measured variant, R11 = 11.83 us]
// One wave (64 threads) per 16 points; grid = P/16 = 2500 blocks.
//   Phase A (VALU): lane l = (pt = l&15, iq = l>>4) computes
//       h[d][i=4*iq+j] = sum_n r[pt][n][d] * feat[nbr[pt][n]][4*iq+j]
//     feat gathered as one dwordx4 per neighbor (16 points covered per instr).
//   Phase B (MFMA): D[16pt][16o] = sum_d H_d(16x16) @ W_d^T(16x16)
//     = 3 chained v_mfma_f32_16x16x16f16. Phase-A layout IS the A-fragment
//     (row=l&15, k=4*(l>>4)+j); W loads form the B-fragment (col=l&15).
//     No h transpose, no LDS round-trip, no second barrier.
// LDS: radii rows padded to 52 floats, bs rows to 20 ints -> 2-way banks (free),
// 16B-aligned for b128. W/h as f16 frags (absmax 0.0625 vs threshold 0.4175).
//
// Session evidence: R5/R7/R10/R11/R12 (scalar-DS / b128-DS / packed-DS / MFMA-64t
// / MFMA-256t) span ~4x per-point instruction work yet all land 11.8-13.9 us
// => fixed per-replay floor (~10 us) + ~2-3 us kernel work. This variant is the
// measured minimum.

typedef _Float16 half4v  __attribute__((ext_vector_type(4)));
typedef float    floatx4 __attribute__((ext_vector_type(4)));

__global__ __launch_bounds__(64) void k_conv(const float* __restrict__ feat,
                                             const float* __restrict__ radii,
                                             const float* __restrict__ W,
                                             const int* __restrict__ bs,
                                             float* __restrict__ out,
                                             int P) {
    __shared__ __align__(16) float s_r[16][52];   // [pt][n*3+d], pad 48->52
    __shared__ __align__(16) int   s_nb[16][20];  // [pt][n],     pad 16->20

    const int l = threadIdx.x;        // 0..63
    const int pbase = blockIdx.x * 16;

    // ---- stage radii: 768 floats = 192 float4, coalesced; lane handles f4 idx l, l+64, l+128
    {
        const size_t lim4 = (size_t)P * 12;
#pragma unroll
        for (int c = 0; c < 3; ++c) {
            const int f4i = c * 64 + l;                   // 0..191
            const size_t gidx = (size_t)pbase * 12 + f4i;
            float4 v = make_float4(0.f, 0.f, 0.f, 0.f);
            if (gidx < lim4) v = reinterpret_cast<const float4*>(radii)[gidx];
            const int row  = f4i / 12;
            const int col4 = f4i - row * 12;
            *reinterpret_cast<float4*>(&s_r[row][col4 * 4]) = v;
        }
    }
    // ---- stage bs: lane l -> row l>>2, cols (l&3)*4..+3 (scalar loads, 4B-aligned source)
    {
        const int row = l >> 2;
        const int c0  = (l & 3) * 4;
        const int p   = pbase + row;
        int4 v = make_int4(0, 0, 0, 0);
        if (p < P) {
            const int* bp = bs + (size_t)p * 17 + 1 + c0;
            v.x = bp[0]; v.y = bp[1]; v.z = bp[2]; v.w = bp[3];
        }
        *reinterpret_cast<int4*>(&s_nb[row][c0]) = v;
    }
    __syncthreads();

    const int pt = l & 15;            // phase-A point row / phase-B output channel col
    const int iq = l >> 4;            // k-quad

    // ---- B-fragments from W (global, L1-hot): B_d[k=i][n=o], lane: o=l&15, i=4*iq+j
    half4v bw0, bw1, bw2;
    {
        const float4* Wv = reinterpret_cast<const float4*>(W);
        const float4 w0 = Wv[  0 + pt * 4 + iq];
        const float4 w1 = Wv[ 64 + pt * 4 + iq];
        const float4 w2 = Wv[128 + pt * 4 + iq];
        bw0[0]=(_Float16)w0.x; bw0[1]=(_Float16)w0.y; bw0[2]=(_Float16)w0.z; bw0[3]=(_Float16)w0.w;
        bw1[0]=(_Float16)w1.x; bw1[1]=(_Float16)w1.y; bw1[2]=(_Float16)w1.z; bw1[3]=(_Float16)w1.w;
        bw2[0]=(_Float16)w2.x; bw2[1]=(_Float16)w2.y; bw2[2]=(_Float16)w2.z; bw2[3]=(_Float16)w2.w;
    }

    // ---- neighbor row for point pt: 4x b128 (4-lane broadcast, 2-way banks)
    int nb[16];
    {
        const int4* nb4 = reinterpret_cast<const int4*>(&s_nb[pt][0]);
#pragma unroll
        for (int c = 0; c < 4; ++c) {
            const int4 v = nb4[c];
            nb[c*4+0] = v.x; nb[c*4+1] = v.y; nb[c*4+2] = v.z; nb[c*4+3] = v.w;
        }
    }

    // ---- Phase A: h[d][j] for i = 4*iq+j ----
    float a00=0.f,a01=0.f,a02=0.f,a03=0.f;   // d=0
    float a10=0.f,a11=0.f,a12=0.f,a13=0.f;   // d=1
    float a20=0.f,a21=0.f,a22=0.f,a23=0.f;   // d=2
    const float4* feat4 = reinterpret_cast<const float4*>(feat);
    const float4* rrow  = reinterpret_cast<const float4*>(&s_r[pt][0]);
#pragma unroll
    for (int c = 0; c < 4; ++c) {
        // flat r row: [n*3+d]; chunk c covers n = 4c..4c+3 (12 floats = 3 float4)
        const float4 r0 = rrow[c*3+0];   // {n0.d0, n0.d1, n0.d2, n1.d0}
        const float4 r1 = rrow[c*3+1];   // {n1.d1, n1.d2, n2.d0, n2.d1}
        const float4 r2 = rrow[c*3+2];   // {n2.d2, n3.d0, n3.d1, n3.d2}
        float4 f;
        f = feat4[(size_t)nb[c*4+0] * 4 + iq];
        a00+=r0.x*f.x; a01+=r0.x*f.y; a02+=r0.x*f.z; a03+=r0.x*f.w;
        a10+=r0.y*f.x; a11+=r0.y*f.y; a12+=r0.y*f.z; a13+=r0.y*f.w;
        a20+=r0.z*f.x; a21+=r0.z*f.y; a22+=r0.z*f.z; a23+=r0.z*f.w;
        f = feat4[(size_t)nb[c*4+1] * 4 + iq];
        a00+=r0.w*f.x; a01+=r0.w*f.y; a02+=r0.w*f.z; a03+=r0.w*f.w;
        a10+=r1.x*f.x; a11+=r1.x*f.y; a12+=r1.x*f.z; a13+=r1.x*f.w;
        a20+=r1.y*f.x; a21+=r1.y*f.y; a22+=r1.y*f.z; a23+=r1.y*f.w;
        f = feat4[(size_t)nb[c*4+2] * 4 + iq];
        a00+=r1.z*f.x; a01+=r1.z*f.y; a02+=r1.z*f.z; a03+=r1.z*f.w;
        a10+=r1.w*f.x; a11+=r1.w*f.y; a12+=r1.w*f.z; a13+=r1.w*f.w;
        a20+=r2.x*f.x; a21+=r2.x*f.y; a22+=r2.x*f.z; a23+=r2.x*f.w;
        f = feat4[(size_t)nb[c*4+3] * 4 + iq];
        a00+=r2.y*f.x; a01+=r2.y*f.y; a02+=r2.y*f.z; a03+=r2.y*f.w;
        a10+=r2.z*f.x; a11+=r2.z*f.y; a12+=r2.z*f.z; a13+=r2.z*f.w;
        a20+=r2.w*f.x; a21+=r2.w*f.y; a22+=r2.w*f.z; a23+=r2.w*f.w;
    }

    // ---- A-fragments (f16) ----
    half4v ah0, ah1, ah2;
    ah0[0]=(_Float16)a00; ah0[1]=(_Float16)a01; ah0[2]=(_Float16)a02; ah0[3]=(_Float16)a03;
    ah1[0]=(_Float16)a10; ah1[1]=(_Float16)a11; ah1[2]=(_Float16)a12; ah1[3]=(_Float16)a13;
    ah2[0]=(_Float16)a20; ah2[1]=(_Float16)a21; ah2[2]=(_Float16)a22; ah2[3]=(_Float16)a23;

    // ---- Phase B: 3 chained MFMAs ----
    floatx4 acc = {0.f, 0.f, 0.f, 0.f};
    acc = __builtin_amdgcn_mfma_f32_16x16x16f16(ah0, bw0, acc, 0, 0, 0);
    acc = __builtin_amdgcn_mfma_f32_16x16x16f16(ah1, bw1, acc, 0, 0, 0);
    acc = __builtin_amdgcn_mfma_f32_16x16x16f16(ah2, bw2, acc, 0, 0, 0);

    // ---- store: D col = l&15 (=o), row = 4*(l>>4)+j (= point) ----
#pragma unroll
    for (int j = 0; j < 4; ++j) {
        const int prow = pbase + 4 * iq + j;
        if (prow < P) out[(size_t)prow * 16 + pt] = acc[j];
    }
}

extern "C" void kernel_launch(void* const* d_in, const int* in_sizes, int n_in,
                              void* d_out, int out_size, void* d_ws, size_t ws_size,
                              hipStream_t stream) {
    const float* feat  = (const float*)d_in[0];   // [P,16] f32
    const float* radii = (const float*)d_in[1];   // [E,3]  f32
    const float* W     = (const float*)d_in[2];   // [3,16,16] f32
    const int*   bs    = (const int*)d_in[3];     // [P,17] i32
    float* out = (float*)d_out;                   // [P,16] f32

    const int P = in_sizes[0] / 16;
    const int grid = (P + 15) / 16;
    k_conv<<<grid, 64, 0, stream>>>(feat, radii, W, bs, out, P);
}